// Round 1
// baseline (1216.478 us; speedup 1.0000x reference)
//
#include <hip/hip_runtime.h>

// Upsampling 2x nearest-neighbor: (16,64,256,256) fp32 -> (16,64,512,512) fp32.
// Pure data movement, HBM-bound. Ideal traffic 1.34 GB -> ~215 us @ 6.3 TB/s.
//
// v2: persistent grid-stride kernel. Previous one-shot version (1178.9 us,
// ~1.14 TB/s) had 1 load in flight per wave and 524K short-lived waves ->
// latency/churn-bound, not BW-bound. Now: 2048 blocks x 256 threads
// (8 blocks/CU), each thread handles 64 float2 inputs, unrolled x8 so 8
// independent 8B loads issue before their 16 dependent 16B stores.
// col is loop-invariant (NTHREADS % 128 == 0); pointers advance by
// compile-time strides -> minimal address VALU. Nontemporal on both sides
// (write-once stream, no reuse).

using f2v = __attribute__((ext_vector_type(2))) float;
using f4v = __attribute__((ext_vector_type(4))) float;

constexpr int B = 16;
constexpr int C = 64;
constexpr int H = 256;
constexpr int W = 256;
constexpr int SCALE = 2;

constexpr int IN_V2_PER_ROW  = W / 2;              // 128 float2 per input row
constexpr int OUT_V4_PER_ROW = (W * SCALE) / 4;    // 128 float4 per output row
constexpr long long N_IN_V2 = (long long)B * C * H * IN_V2_PER_ROW; // 33,554,432

constexpr int BLOCK = 256;
constexpr int GRID  = 2048;                                 // 8 blocks/CU x 256 CU
constexpr long long NTHREADS = (long long)BLOCK * GRID;     // 524,288
constexpr int ITERS  = (int)(N_IN_V2 / NTHREADS);           // 64
constexpr int UNROLL = 8;

static_assert(N_IN_V2 % NTHREADS == 0, "no tail");
static_assert(ITERS % UNROLL == 0, "clean unroll");
static_assert(NTHREADS % IN_V2_PER_ROW == 0, "col loop-invariant");

// Per grid-stride step: input advances NTHREADS float2 = 4096 input rows;
// output advances 4096*SCALE output rows of 128 float4 each.
constexpr long long OUT_STEP =
    (NTHREADS / IN_V2_PER_ROW) * (long long)SCALE * OUT_V4_PER_ROW; // 1,048,576

__global__ __launch_bounds__(BLOCK)
void Upsampling_68882685493276_kernel(const f2v* __restrict__ in,
                                      f4v* __restrict__ out) {
    const long long t0 = (long long)blockIdx.x * BLOCK + threadIdx.x;
    const int col      = (int)(t0 & (IN_V2_PER_ROW - 1));   // loop-invariant
    const long long r0 = t0 >> 7;                           // input row

    const f2v* ip = in + t0;
    f4v* op = out + r0 * SCALE * OUT_V4_PER_ROW + col;

    for (int k = 0; k < ITERS; k += UNROLL) {
        f2v v[UNROLL];
        #pragma unroll
        for (int u = 0; u < UNROLL; ++u)
            v[u] = __builtin_nontemporal_load(ip + (long long)u * NTHREADS);

        #pragma unroll
        for (int u = 0; u < UNROLL; ++u) {
            f4v o = {v[u].x, v[u].x, v[u].y, v[u].y};
            f4v* p = op + (long long)u * OUT_STEP;
            __builtin_nontemporal_store(o, p);                    // output row 2r
            __builtin_nontemporal_store(o, p + OUT_V4_PER_ROW);   // output row 2r+1
        }

        ip += (long long)UNROLL * NTHREADS;
        op += (long long)UNROLL * OUT_STEP;
    }
}

extern "C" void kernel_launch(void* const* d_in, const int* in_sizes, int n_in,
                              void* d_out, int out_size, void* d_ws, size_t ws_size,
                              hipStream_t stream) {
    const f2v* in = (const f2v*)d_in[0];
    f4v* out = (f4v*)d_out;
    Upsampling_68882685493276_kernel<<<dim3(GRID), dim3(BLOCK), 0, stream>>>(in, out);
}